// Round 4
// baseline (195.943 us; speedup 1.0000x reference)
//
#include <hip/hip_runtime.h>
#include <hip/hip_bf16.h>
#include <math.h>

// Problem constants
#define BDEF 64
#define LSEQ 256
#define HD   4
#define NST  4
#define NBLK 2

typedef float nfloat4 __attribute__((ext_vector_type(4)));  // native vec for nt ops

__device__ inline void nt_store4(const float4 v, float* p) {
    nfloat4 nv = {v.x, v.y, v.z, v.w};
    __builtin_nontemporal_store(nv, (nfloat4*)p);
}

// ---------------------------------------------------------------------------
// Kernel 1: K-comp + encoder + 2x S4D block + decoder + pooling
//           -> combined [64,1856].  grid=64 (one block per batch), block=256.
// ---------------------------------------------------------------------------
__global__ __launch_bounds__(256) void s4front(
    const float* __restrict__ x, const float* __restrict__ enc_W,
    const float* __restrict__ enc_b, const float* __restrict__ ln_s,
    const float* __restrict__ ln_b, const float* __restrict__ log_dt,
    const float* __restrict__ A_re, const float* __restrict__ A_im,
    const float* __restrict__ C_re, const float* __restrict__ C_im,
    const float* __restrict__ Dp, const float* __restrict__ out_W,
    const float* __restrict__ out_b, const float* __restrict__ dec_W,
    const float* __restrict__ dec_b, float* __restrict__ combined)
{
    const int b = blockIdx.x;
    const int l = threadIdx.x;
    __shared__ float Kl[NBLK][LSEQ][4];   // conv kernels, 8 KB
    __shared__ float x_lds[4][256];       // raw input row
    __shared__ float z_lds[256][4];       // pre-conv activations ([l][h], b128)
    __shared__ float s4_lds[256][4];      // decoder output for pooling

    // ---- compute SSM kernels K[i][m][h] (thread m = l) ----
    {
        const float t = (float)l;
        for (int i = 0; i < NBLK; ++i) {
            #pragma unroll
            for (int h = 0; h < HD; ++h) {
                float dt = expf(log_dt[i*HD + h]);
                float acc = 0.f;
                #pragma unroll
                for (int n = 0; n < NST; ++n) {
                    const int idx = (i*HD + h)*NST + n;
                    float ar = -expf(A_re[idx]);     // Re(A)
                    float ai = A_im[idx];            // Im(A)
                    float dr = ar*dt, di = ai*dt;    // dtA
                    float er  = expf(dr);            // Bd = (exp(dtA)-1)/A
                    float e1r = er*cosf(di) - 1.0f;
                    float e1i = er*sinf(di);
                    float inv = 1.0f/(ar*ar + ai*ai);
                    float bdr = (e1r*ar + e1i*ai)*inv;
                    float bdi = (e1i*ar - e1r*ai)*inv;
                    float cr = C_re[idx], ci = C_im[idx];
                    float cbr = cr*bdr - ci*bdi;     // C*Bd
                    float cbi = cr*bdi + ci*bdr;
                    float em = expf(dr*t);           // vand = exp(dtA*t)
                    float vr = em*cosf(di*t);
                    float vi = em*sinf(di*t);
                    acc += cbr*vr - cbi*vi;
                }
                Kl[i][l][h] = 2.0f*acc;
            }
        }
    }

    #pragma unroll
    for (int c = 0; c < 4; ++c)
        x_lds[c][l] = x[(b*4 + c)*256 + l];

    // encoder: u[h] = sum_c x[c,l]*enc_W[c,h] + enc_b[h]
    float u[4];
    #pragma unroll
    for (int h = 0; h < 4; ++h) {
        float a = enc_b[h];
        #pragma unroll
        for (int c = 0; c < 4; ++c) a += x_lds[c][l]*enc_W[c*4 + h];
        u[h] = a;
    }
    __syncthreads();

    for (int i = 0; i < NBLK; ++i) {
        // prenorm LN over H=4
        float mu = 0.25f*(u[0]+u[1]+u[2]+u[3]);
        float var = 0.f;
        #pragma unroll
        for (int h = 0; h < 4; ++h) { float d = u[h]-mu; var += d*d; }
        var *= 0.25f;
        float rs = rsqrtf(var + 1e-5f);
        float z[4];
        #pragma unroll
        for (int h = 0; h < 4; ++h)
            z[h] = (u[h]-mu)*rs*ln_s[i*4 + h] + ln_b[i*4 + h];
        *(float4*)&z_lds[l][0] = make_float4(z[0], z[1], z[2], z[3]);
        __syncthreads();

        // causal convolution: y[h] = sum_{m<=l} K[i][m][h]*z[l-m][h]
        float y0 = 0.f, y1 = 0.f, y2 = 0.f, y3 = 0.f;
        const int mlim = l | 63;   // wave-uniform upper bound
        #pragma unroll 4
        for (int m = 0; m <= mlim; ++m) {
            float4 kk = *(const float4*)&Kl[i][m][0];  // uniform -> broadcast
            int p = (l - m) & 255;                     // safe wrap (masked tail)
            float4 zz = *(const float4*)&z_lds[p][0];
            if (m <= l) {
                y0 += kk.x*zz.x; y1 += kk.y*zz.y;
                y2 += kk.z*zz.z; y3 += kk.w*zz.w;
            }
        }
        float y[4] = {y0, y1, y2, y3};
        // skip + gelu (tanh approximation, jax.nn.gelu default)
        #pragma unroll
        for (int h = 0; h < 4; ++h) {
            float v = y[h] + Dp[i*4 + h]*z[h];
            float inner = 0.7978845608028654f*(v + 0.044715f*v*v*v);
            y[h] = 0.5f*v*(1.0f + tanhf(inner));
        }
        // output projection over h + residual
        #pragma unroll
        for (int k = 0; k < 4; ++k) {
            float a = out_b[i*4 + k];
            #pragma unroll
            for (int h = 0; h < 4; ++h) a += y[h]*out_W[(i*4 + h)*4 + k];
            u[k] += a;
        }
        __syncthreads();   // protect z_lds before next iteration overwrite
    }

    // decoder
    #pragma unroll
    for (int h = 0; h < 4; ++h) {
        float a = dec_b[h];
        #pragma unroll
        for (int k = 0; k < 4; ++k) a += u[k]*dec_W[k*4 + h];
        s4_lds[l][h] = a;
    }
    __syncthreads();

    float* cmb = combined + b*1856;
    // z16: [4,16] pooled (window 16), flattened h*16+k
    if (l < 64) {
        int h = l >> 4, kk = l & 15;
        float a = 0.f;
        #pragma unroll
        for (int j = 0; j < 16; ++j) a += s4_lds[kk*16 + j][h];
        cmb[l] = a*(1.0f/16.0f);
    }
    // fpp: [4,448] = concat(pool64(win4), pool128(win2), raw256), offset 64
    for (int e = l; e < 1792; e += 256) {
        int c = e/448, jj = e%448;
        float v;
        if (jj < 64) {
            v = 0.25f*(x_lds[c][4*jj] + x_lds[c][4*jj+1] +
                       x_lds[c][4*jj+2] + x_lds[c][4*jj+3]);
        } else if (jj < 192) {
            int q = jj - 64;
            v = 0.5f*(x_lds[c][2*q] + x_lds[c][2*q+1]);
        } else {
            v = x_lds[c][jj - 192];
        }
        cmb[64 + e] = v;
    }
}

// ---------------------------------------------------------------------------
// Kernel 2/4: partial GEMM, M=64 fixed. Block = [KCH k-chunk] x [64 j-tile],
// writes parts[ks][64][NCOLS] (nontemporal). grid = (K/KCH, NCOLS/64).
// Each thread computes a 4b x 4j micro-tile.
// ---------------------------------------------------------------------------
template<int NCOLS, int ASTRIDE, int KCH>
__global__ __launch_bounds__(256) void mlp_part(
    const float* __restrict__ A, const float* __restrict__ W,
    float* __restrict__ parts)
{
    __shared__ float At[64][KCH + 4];  // A chunk, [b][k], padded
    __shared__ float Wl[KCH][64];      // W tile [k][j]
    const int ks = blockIdx.x, k0 = ks*KCH;
    const int j0 = blockIdx.y*64;
    const int t  = threadIdx.x;

    // stage A[64][KCH]: 64*KCH/4 float4, KCH/4 per row
    {
        constexpr int AF4 = 64*KCH/4;
        constexpr int RF4 = KCH/4;
        #pragma unroll
        for (int f = t; f < AF4; f += 256) {
            const int row = f / RF4, c4 = f % RF4;
            *(float4*)&At[row][c4*4] =
                *(const float4*)(A + (size_t)row*ASTRIDE + k0 + c4*4);
        }
        // stage W[KCH][64]: KCH*16 float4, 16 per row
        constexpr int WF4 = KCH*16;
        #pragma unroll
        for (int f = t; f < WF4; f += 256) {
            const int row = f >> 4, c4 = f & 15;
            *(float4*)&Wl[row][c4*4] =
                *(const float4*)(W + (size_t)(k0 + row)*NCOLS + j0 + c4*4);
        }
    }
    __syncthreads();

    const int bi = t >> 4, ji = t & 15;
    const int br = bi*4;
    float4 acc0 = {0,0,0,0}, acc1 = {0,0,0,0}, acc2 = {0,0,0,0}, acc3 = {0,0,0,0};
    #pragma unroll 8
    for (int k = 0; k < KCH; ++k) {
        float4 wv = *(const float4*)&Wl[k][ji*4];
        float a0 = At[br+0][k], a1 = At[br+1][k];
        float a2 = At[br+2][k], a3 = At[br+3][k];
        acc0.x += a0*wv.x; acc0.y += a0*wv.y; acc0.z += a0*wv.z; acc0.w += a0*wv.w;
        acc1.x += a1*wv.x; acc1.y += a1*wv.y; acc1.z += a1*wv.z; acc1.w += a1*wv.w;
        acc2.x += a2*wv.x; acc2.y += a2*wv.y; acc2.z += a2*wv.z; acc2.w += a2*wv.w;
        acc3.x += a3*wv.x; acc3.y += a3*wv.y; acc3.z += a3*wv.z; acc3.w += a3*wv.w;
    }
    float* pbase = parts + (size_t)(ks*64 + br)*NCOLS + j0 + ji*4;
    nt_store4(acc0, pbase);
    nt_store4(acc1, pbase + NCOLS);
    nt_store4(acc2, pbase + 2*NCOLS);
    nt_store4(acc3, pbase + 3*NCOLS);
}

// ---------------------------------------------------------------------------
// Kernel 3/5: sum partials + bias, then LayerNorm + ReLU.  grid=64 (per b).
// ---------------------------------------------------------------------------
template<int N>
__global__ __launch_bounds__(256) void reduce_ln_relu(
    const float* __restrict__ parts, const float* __restrict__ bias,
    const float* __restrict__ g, const float* __restrict__ be,
    float* __restrict__ out, int KS)
{
    constexpr int NV = N/1024;      // float4 per thread
    const int b = blockIdx.x, t = threadIdx.x;
    float4 acc[NV];
    #pragma unroll
    for (int v = 0; v < NV; ++v)
        acc[v] = *(const float4*)(bias + v*1024 + t*4);
    for (int ks = 0; ks < KS; ++ks) {
        const float* p = parts + (size_t)(ks*64 + b)*N;
        #pragma unroll
        for (int v = 0; v < NV; ++v) {
            float4 q = *(const float4*)(p + v*1024 + t*4);
            acc[v].x += q.x; acc[v].y += q.y; acc[v].z += q.z; acc[v].w += q.w;
        }
    }
    float s = 0.f, s2 = 0.f;
    #pragma unroll
    for (int v = 0; v < NV; ++v) {
        s  += acc[v].x + acc[v].y + acc[v].z + acc[v].w;
        s2 += acc[v].x*acc[v].x + acc[v].y*acc[v].y +
              acc[v].z*acc[v].z + acc[v].w*acc[v].w;
    }
    #pragma unroll
    for (int off = 32; off > 0; off >>= 1) {
        s  += __shfl_down(s,  off);
        s2 += __shfl_down(s2, off);
    }
    __shared__ float red[2][4];
    const int w = t >> 6;
    if ((t & 63) == 0) { red[0][w] = s; red[1][w] = s2; }
    __syncthreads();
    float ts  = red[0][0] + red[0][1] + red[0][2] + red[0][3];
    float ts2 = red[1][0] + red[1][1] + red[1][2] + red[1][3];
    const float inv_n = 1.0f/(float)N;
    float mu  = ts*inv_n;
    float var = ts2*inv_n - mu*mu;
    float rs  = rsqrtf(var + 1e-5f);
    #pragma unroll
    for (int v = 0; v < NV; ++v) {
        const int j = v*1024 + t*4;
        float4 gv  = *(const float4*)(g + j);
        float4 bev = *(const float4*)(be + j);
        float4 o;
        o.x = fmaxf((acc[v].x - mu)*rs*gv.x + bev.x, 0.f);
        o.y = fmaxf((acc[v].y - mu)*rs*gv.y + bev.y, 0.f);
        o.z = fmaxf((acc[v].z - mu)*rs*gv.z + bev.z, 0.f);
        o.w = fmaxf((acc[v].w - mu)*rs*gv.w + bev.w, 0.f);
        *(float4*)(out + (size_t)b*N + j) = o;
    }
}

// ---------------------------------------------------------------------------
// Kernel 6: out[b,s,:] = h2[b, s*8 .. s*8+7] @ W3 + b3 -> [64,512,4096] f32
// grid = (512 row-groups of 64 rows, 4 j-slices of 1024), block 256.
// ---------------------------------------------------------------------------
#define ROWS_D 64
__global__ __launch_bounds__(256) void final_mm(
    const float* __restrict__ h2, const float* __restrict__ W3,
    const float* __restrict__ b3, float* __restrict__ out)
{
    const int rg = blockIdx.x;
    const int js = blockIdx.y;
    const int t  = threadIdx.x;
    __shared__ float h_lds[ROWS_D*8];
    const int bs0 = rg*ROWS_D;
    for (int e = t; e < ROWS_D*8; e += 256) h_lds[e] = h2[bs0*8 + e];
    __syncthreads();
    const int j = js*1024 + t*4;
    float4 w[8];
    #pragma unroll
    for (int k = 0; k < 8; ++k) w[k] = *(const float4*)(W3 + k*4096 + j);
    const float4 bv = *(const float4*)(b3 + j);
    for (int r = 0; r < ROWS_D; ++r) {
        float4 acc = bv;
        #pragma unroll
        for (int k = 0; k < 8; ++k) {
            float hv = h_lds[r*8 + k];
            acc.x += hv*w[k].x; acc.y += hv*w[k].y;
            acc.z += hv*w[k].z; acc.w += hv*w[k].w;
        }
        nt_store4(acc, out + (size_t)(bs0 + r)*4096 + j);
    }
}

// ---------------------------------------------------------------------------
extern "C" void kernel_launch(void* const* d_in, const int* in_sizes, int n_in,
                              void* d_out, int out_size, void* d_ws, size_t ws_size,
                              hipStream_t stream) {
    const float* x      = (const float*)d_in[0];
    const float* enc_W  = (const float*)d_in[1];
    const float* enc_b  = (const float*)d_in[2];
    const float* ln_s   = (const float*)d_in[3];
    const float* ln_b   = (const float*)d_in[4];
    const float* log_dt = (const float*)d_in[5];
    const float* A_re   = (const float*)d_in[6];
    const float* A_im   = (const float*)d_in[7];
    const float* C_re   = (const float*)d_in[8];
    const float* C_im   = (const float*)d_in[9];
    const float* Dp     = (const float*)d_in[10];
    const float* out_W  = (const float*)d_in[11];
    const float* out_b  = (const float*)d_in[12];
    const float* dec_W  = (const float*)d_in[13];
    const float* dec_b  = (const float*)d_in[14];
    const float* W1     = (const float*)d_in[15];
    const float* b1     = (const float*)d_in[16];
    const float* g1     = (const float*)d_in[17];
    const float* be1    = (const float*)d_in[18];
    const float* W2     = (const float*)d_in[19];
    const float* b2     = (const float*)d_in[20];
    const float* g2     = (const float*)d_in[21];
    const float* be2    = (const float*)d_in[22];
    const float* W3     = (const float*)d_in[23];
    const float* b3     = (const float*)d_in[24];
    float* out = (float*)d_out;

    float* ws = (float*)d_ws;
    float* combined = ws;                        // 64*1856      = 118,784
    float* parts1   = combined + 64*1856;        // 29*64*1024   = 1,900,544
    float* h1       = parts1 + 29*64*1024;       // 64*1024      = 65,536
    float* parts2   = h1 + 64*1024;              // 8*64*4096    = 2,097,152
    float* h2       = parts2 + 8*64*4096;        // 64*4096      = 262,144

    s4front<<<64, 256, 0, stream>>>(x, enc_W, enc_b, ln_s, ln_b, log_dt,
                                    A_re, A_im, C_re, C_im, Dp,
                                    out_W, out_b, dec_W, dec_b, combined);
    mlp_part<1024,1856,64><<<dim3(29,16), 256, 0, stream>>>(combined, W1, parts1);
    reduce_ln_relu<1024><<<64, 256, 0, stream>>>(parts1, b1, g1, be1, h1, 29);
    mlp_part<4096,1024,128><<<dim3(8,64), 256, 0, stream>>>(h1, W2, parts2);
    reduce_ln_relu<4096><<<64, 256, 0, stream>>>(parts2, b2, g2, be2, h2, 8);
    final_mm<<<dim3(512,4), 256, 0, stream>>>(h2, W3, b3, out);
}

// Round 5
// 187.712 us; speedup vs baseline: 1.0438x; 1.0438x over previous
//
#include <hip/hip_runtime.h>
#include <hip/hip_bf16.h>
#include <math.h>

// Problem constants
#define BDEF 64
#define LSEQ 256
#define HD   4
#define NST  4
#define NBLK 2

typedef float nfloat4 __attribute__((ext_vector_type(4)));  // native vec for nt ops

__device__ inline void nt_store4(const float4 v, float* p) {
    nfloat4 nv = {v.x, v.y, v.z, v.w};
    __builtin_nontemporal_store(nv, (nfloat4*)p);
}

// ---------------------------------------------------------------------------
// Kernel 1: K-comp + encoder + 2x S4D block + decoder + pooling
//           -> combined [64,1856].  grid=64 (one block per batch), block=256.
// ---------------------------------------------------------------------------
__global__ __launch_bounds__(256) void s4front(
    const float* __restrict__ x, const float* __restrict__ enc_W,
    const float* __restrict__ enc_b, const float* __restrict__ ln_s,
    const float* __restrict__ ln_b, const float* __restrict__ log_dt,
    const float* __restrict__ A_re, const float* __restrict__ A_im,
    const float* __restrict__ C_re, const float* __restrict__ C_im,
    const float* __restrict__ Dp, const float* __restrict__ out_W,
    const float* __restrict__ out_b, const float* __restrict__ dec_W,
    const float* __restrict__ dec_b, float* __restrict__ combined)
{
    const int b = blockIdx.x;
    const int l = threadIdx.x;
    __shared__ float Kl[NBLK][LSEQ][4];   // conv kernels, 8 KB
    __shared__ float x_lds[4][256];       // raw input row
    __shared__ float z_lds[256][4];       // pre-conv activations ([l][h], b128)
    __shared__ float s4_lds[256][4];      // decoder output for pooling

    // ---- compute SSM kernels K[i][m][h] (thread m = l) ----
    {
        const float t = (float)l;
        for (int i = 0; i < NBLK; ++i) {
            #pragma unroll
            for (int h = 0; h < HD; ++h) {
                float dt = expf(log_dt[i*HD + h]);
                float acc = 0.f;
                #pragma unroll
                for (int n = 0; n < NST; ++n) {
                    const int idx = (i*HD + h)*NST + n;
                    float ar = -expf(A_re[idx]);     // Re(A)
                    float ai = A_im[idx];            // Im(A)
                    float dr = ar*dt, di = ai*dt;    // dtA
                    float er  = expf(dr);            // Bd = (exp(dtA)-1)/A
                    float e1r = er*cosf(di) - 1.0f;
                    float e1i = er*sinf(di);
                    float inv = 1.0f/(ar*ar + ai*ai);
                    float bdr = (e1r*ar + e1i*ai)*inv;
                    float bdi = (e1i*ar - e1r*ai)*inv;
                    float cr = C_re[idx], ci = C_im[idx];
                    float cbr = cr*bdr - ci*bdi;     // C*Bd
                    float cbi = cr*bdi + ci*bdr;
                    float em = expf(dr*t);           // vand = exp(dtA*t)
                    float vr = em*cosf(di*t);
                    float vi = em*sinf(di*t);
                    acc += cbr*vr - cbi*vi;
                }
                Kl[i][l][h] = 2.0f*acc;
            }
        }
    }

    #pragma unroll
    for (int c = 0; c < 4; ++c)
        x_lds[c][l] = x[(b*4 + c)*256 + l];

    // encoder: u[h] = sum_c x[c,l]*enc_W[c,h] + enc_b[h]
    float u[4];
    #pragma unroll
    for (int h = 0; h < 4; ++h) {
        float a = enc_b[h];
        #pragma unroll
        for (int c = 0; c < 4; ++c) a += x_lds[c][l]*enc_W[c*4 + h];
        u[h] = a;
    }
    __syncthreads();

    for (int i = 0; i < NBLK; ++i) {
        // prenorm LN over H=4
        float mu = 0.25f*(u[0]+u[1]+u[2]+u[3]);
        float var = 0.f;
        #pragma unroll
        for (int h = 0; h < 4; ++h) { float d = u[h]-mu; var += d*d; }
        var *= 0.25f;
        float rs = rsqrtf(var + 1e-5f);
        float z[4];
        #pragma unroll
        for (int h = 0; h < 4; ++h)
            z[h] = (u[h]-mu)*rs*ln_s[i*4 + h] + ln_b[i*4 + h];
        *(float4*)&z_lds[l][0] = make_float4(z[0], z[1], z[2], z[3]);
        __syncthreads();

        // causal convolution: y[h] = sum_{m<=l} K[i][m][h]*z[l-m][h]
        float y0 = 0.f, y1 = 0.f, y2 = 0.f, y3 = 0.f;
        const int mlim = l | 63;   // wave-uniform upper bound
        #pragma unroll 4
        for (int m = 0; m <= mlim; ++m) {
            float4 kk = *(const float4*)&Kl[i][m][0];  // uniform -> broadcast
            int p = (l - m) & 255;                     // safe wrap (masked tail)
            float4 zz = *(const float4*)&z_lds[p][0];
            if (m <= l) {
                y0 += kk.x*zz.x; y1 += kk.y*zz.y;
                y2 += kk.z*zz.z; y3 += kk.w*zz.w;
            }
        }
        float y[4] = {y0, y1, y2, y3};
        // skip + gelu (tanh approximation, jax.nn.gelu default)
        #pragma unroll
        for (int h = 0; h < 4; ++h) {
            float v = y[h] + Dp[i*4 + h]*z[h];
            float inner = 0.7978845608028654f*(v + 0.044715f*v*v*v);
            y[h] = 0.5f*v*(1.0f + tanhf(inner));
        }
        // output projection over h + residual
        #pragma unroll
        for (int k = 0; k < 4; ++k) {
            float a = out_b[i*4 + k];
            #pragma unroll
            for (int h = 0; h < 4; ++h) a += y[h]*out_W[(i*4 + h)*4 + k];
            u[k] += a;
        }
        __syncthreads();   // protect z_lds before next iteration overwrite
    }

    // decoder
    #pragma unroll
    for (int h = 0; h < 4; ++h) {
        float a = dec_b[h];
        #pragma unroll
        for (int k = 0; k < 4; ++k) a += u[k]*dec_W[k*4 + h];
        s4_lds[l][h] = a;
    }
    __syncthreads();

    float* cmb = combined + b*1856;
    // z16: [4,16] pooled (window 16), flattened h*16+k
    if (l < 64) {
        int h = l >> 4, kk = l & 15;
        float a = 0.f;
        #pragma unroll
        for (int j = 0; j < 16; ++j) a += s4_lds[kk*16 + j][h];
        cmb[l] = a*(1.0f/16.0f);
    }
    // fpp: [4,448] = concat(pool64(win4), pool128(win2), raw256), offset 64
    for (int e = l; e < 1792; e += 256) {
        int c = e/448, jj = e%448;
        float v;
        if (jj < 64) {
            v = 0.25f*(x_lds[c][4*jj] + x_lds[c][4*jj+1] +
                       x_lds[c][4*jj+2] + x_lds[c][4*jj+3]);
        } else if (jj < 192) {
            int q = jj - 64;
            v = 0.5f*(x_lds[c][2*q] + x_lds[c][2*q+1]);
        } else {
            v = x_lds[c][jj - 192];
        }
        cmb[64 + e] = v;
    }
}

// ---------------------------------------------------------------------------
// Kernel 2/4: partial GEMM, M=64 fixed. Block = [KCH k-chunk] x [64 j-tile],
// writes parts[ks][64][NCOLS]. grid = (K/KCH, NCOLS/64), block 256.
// Each thread computes a 4b x 4j micro-tile. Regular stores (L2-resident
// for the following reduce kernel).
// ---------------------------------------------------------------------------
template<int NCOLS, int ASTRIDE, int KCH>
__global__ __launch_bounds__(256) void mlp_part(
    const float* __restrict__ A, const float* __restrict__ W,
    float* __restrict__ parts)
{
    __shared__ float At[64][KCH + 4];  // A chunk, [b][k], padded
    __shared__ float Wl[KCH][64];      // W tile [k][j]
    const int ks = blockIdx.x, k0 = ks*KCH;
    const int j0 = blockIdx.y*64;
    const int t  = threadIdx.x;

    // stage A[64][KCH]: 64*KCH/4 float4, KCH/4 per row
    {
        constexpr int AF4 = 64*KCH/4;
        constexpr int RF4 = KCH/4;
        #pragma unroll
        for (int f = t; f < AF4; f += 256) {
            const int row = f / RF4, c4 = f % RF4;
            *(float4*)&At[row][c4*4] =
                *(const float4*)(A + (size_t)row*ASTRIDE + k0 + c4*4);
        }
        // stage W[KCH][64]: KCH*16 float4, 16 per row
        constexpr int WF4 = KCH*16;
        #pragma unroll
        for (int f = t; f < WF4; f += 256) {
            const int row = f >> 4, c4 = f & 15;
            *(float4*)&Wl[row][c4*4] =
                *(const float4*)(W + (size_t)(k0 + row)*NCOLS + j0 + c4*4);
        }
    }
    __syncthreads();

    const int bi = t >> 4, ji = t & 15;
    const int br = bi*4;
    float4 acc0 = {0,0,0,0}, acc1 = {0,0,0,0}, acc2 = {0,0,0,0}, acc3 = {0,0,0,0};
    #pragma unroll 8
    for (int k = 0; k < KCH; ++k) {
        float4 wv = *(const float4*)&Wl[k][ji*4];
        float a0 = At[br+0][k], a1 = At[br+1][k];
        float a2 = At[br+2][k], a3 = At[br+3][k];
        acc0.x += a0*wv.x; acc0.y += a0*wv.y; acc0.z += a0*wv.z; acc0.w += a0*wv.w;
        acc1.x += a1*wv.x; acc1.y += a1*wv.y; acc1.z += a1*wv.z; acc1.w += a1*wv.w;
        acc2.x += a2*wv.x; acc2.y += a2*wv.y; acc2.z += a2*wv.z; acc2.w += a2*wv.w;
        acc3.x += a3*wv.x; acc3.y += a3*wv.y; acc3.z += a3*wv.z; acc3.w += a3*wv.w;
    }
    float* pbase = parts + (size_t)(ks*64 + br)*NCOLS + j0 + ji*4;
    *(float4*)(pbase)             = acc0;
    *(float4*)(pbase + NCOLS)     = acc1;
    *(float4*)(pbase + 2*NCOLS)   = acc2;
    *(float4*)(pbase + 3*NCOLS)   = acc3;
}

// ---------------------------------------------------------------------------
// Kernel 3/5: sum partials + bias, then LayerNorm + ReLU.  grid=64 (per b).
// ---------------------------------------------------------------------------
template<int N>
__global__ __launch_bounds__(256) void reduce_ln_relu(
    const float* __restrict__ parts, const float* __restrict__ bias,
    const float* __restrict__ g, const float* __restrict__ be,
    float* __restrict__ out, int KS)
{
    constexpr int NV = N/1024;      // float4 per thread
    const int b = blockIdx.x, t = threadIdx.x;
    float4 acc[NV];
    #pragma unroll
    for (int v = 0; v < NV; ++v)
        acc[v] = *(const float4*)(bias + v*1024 + t*4);
    for (int ks = 0; ks < KS; ++ks) {
        const float* p = parts + (size_t)(ks*64 + b)*N;
        #pragma unroll
        for (int v = 0; v < NV; ++v) {
            float4 q = *(const float4*)(p + v*1024 + t*4);
            acc[v].x += q.x; acc[v].y += q.y; acc[v].z += q.z; acc[v].w += q.w;
        }
    }
    float s = 0.f, s2 = 0.f;
    #pragma unroll
    for (int v = 0; v < NV; ++v) {
        s  += acc[v].x + acc[v].y + acc[v].z + acc[v].w;
        s2 += acc[v].x*acc[v].x + acc[v].y*acc[v].y +
              acc[v].z*acc[v].z + acc[v].w*acc[v].w;
    }
    #pragma unroll
    for (int off = 32; off > 0; off >>= 1) {
        s  += __shfl_down(s,  off);
        s2 += __shfl_down(s2, off);
    }
    __shared__ float red[2][4];
    const int w = t >> 6;
    if ((t & 63) == 0) { red[0][w] = s; red[1][w] = s2; }
    __syncthreads();
    float ts  = red[0][0] + red[0][1] + red[0][2] + red[0][3];
    float ts2 = red[1][0] + red[1][1] + red[1][2] + red[1][3];
    const float inv_n = 1.0f/(float)N;
    float mu  = ts*inv_n;
    float var = ts2*inv_n - mu*mu;
    float rs  = rsqrtf(var + 1e-5f);
    #pragma unroll
    for (int v = 0; v < NV; ++v) {
        const int j = v*1024 + t*4;
        float4 gv  = *(const float4*)(g + j);
        float4 bev = *(const float4*)(be + j);
        float4 o;
        o.x = fmaxf((acc[v].x - mu)*rs*gv.x + bev.x, 0.f);
        o.y = fmaxf((acc[v].y - mu)*rs*gv.y + bev.y, 0.f);
        o.z = fmaxf((acc[v].z - mu)*rs*gv.z + bev.z, 0.f);
        o.w = fmaxf((acc[v].w - mu)*rs*gv.w + bev.w, 0.f);
        *(float4*)(out + (size_t)b*N + j) = o;
    }
}

// ---------------------------------------------------------------------------
// Kernel 6: out[b,s,:] = h2[b, s*8 .. s*8+7] @ W3 + b3 -> [64,512,4096] f32
// grid = (512 row-groups of 64 rows, 4 j-slices of 1024), block 256.
// h2 reads are wave-uniform -> scalar-cache s_load path; NO LDS, no barrier.
// ---------------------------------------------------------------------------
#define ROWS_D 64
__global__ __launch_bounds__(256) void final_mm(
    const float* __restrict__ h2, const float* __restrict__ W3,
    const float* __restrict__ b3, float* __restrict__ out)
{
    const int rg = blockIdx.x;
    const int js = blockIdx.y;
    const int t  = threadIdx.x;
    const int bs0 = rg*ROWS_D;
    const int j = js*1024 + t*4;
    float4 w[8];
    #pragma unroll
    for (int k = 0; k < 8; ++k) w[k] = *(const float4*)(W3 + k*4096 + j);
    const float4 bv = *(const float4*)(b3 + j);
    const float* __restrict__ hrow = h2 + (size_t)bs0*8;
    float* __restrict__ obase = out + (size_t)bs0*4096 + j;
    #pragma unroll 4
    for (int r = 0; r < ROWS_D; ++r) {
        float4 acc = bv;
        #pragma unroll
        for (int k = 0; k < 8; ++k) {
            const float hv = hrow[r*8 + k];   // wave-uniform -> s_load (K$)
            acc.x += hv*w[k].x; acc.y += hv*w[k].y;
            acc.z += hv*w[k].z; acc.w += hv*w[k].w;
        }
        nt_store4(acc, obase + (size_t)r*4096);
    }
}

// ---------------------------------------------------------------------------
extern "C" void kernel_launch(void* const* d_in, const int* in_sizes, int n_in,
                              void* d_out, int out_size, void* d_ws, size_t ws_size,
                              hipStream_t stream) {
    const float* x      = (const float*)d_in[0];
    const float* enc_W  = (const float*)d_in[1];
    const float* enc_b  = (const float*)d_in[2];
    const float* ln_s   = (const float*)d_in[3];
    const float* ln_b   = (const float*)d_in[4];
    const float* log_dt = (const float*)d_in[5];
    const float* A_re   = (const float*)d_in[6];
    const float* A_im   = (const float*)d_in[7];
    const float* C_re   = (const float*)d_in[8];
    const float* C_im   = (const float*)d_in[9];
    const float* Dp     = (const float*)d_in[10];
    const float* out_W  = (const float*)d_in[11];
    const float* out_b  = (const float*)d_in[12];
    const float* dec_W  = (const float*)d_in[13];
    const float* dec_b  = (const float*)d_in[14];
    const float* W1     = (const float*)d_in[15];
    const float* b1     = (const float*)d_in[16];
    const float* g1     = (const float*)d_in[17];
    const float* be1    = (const float*)d_in[18];
    const float* W2     = (const float*)d_in[19];
    const float* b2     = (const float*)d_in[20];
    const float* g2     = (const float*)d_in[21];
    const float* be2    = (const float*)d_in[22];
    const float* W3     = (const float*)d_in[23];
    const float* b3     = (const float*)d_in[24];
    float* out = (float*)d_out;

    float* ws = (float*)d_ws;
    float* combined = ws;                        // 64*1856      = 118,784
    float* parts1   = combined + 64*1856;        // 29*64*1024   = 1,900,544
    float* h1       = parts1 + 29*64*1024;       // 64*1024      = 65,536
    float* parts2   = h1 + 64*1024;              // 8*64*4096    = 2,097,152
    float* h2       = parts2 + 8*64*4096;        // 64*4096      = 262,144

    s4front<<<64, 256, 0, stream>>>(x, enc_W, enc_b, ln_s, ln_b, log_dt,
                                    A_re, A_im, C_re, C_im, Dp,
                                    out_W, out_b, dec_W, dec_b, combined);
    mlp_part<1024,1856,64><<<dim3(29,16), 256, 0, stream>>>(combined, W1, parts1);
    reduce_ln_relu<1024><<<64, 256, 0, stream>>>(parts1, b1, g1, be1, h1, 29);
    mlp_part<4096,1024,128><<<dim3(8,64), 256, 0, stream>>>(h1, W2, parts2);
    reduce_ln_relu<4096><<<64, 256, 0, stream>>>(parts2, b2, g2, be2, h2, 8);
    final_mm<<<dim3(512,4), 256, 0, stream>>>(h2, W3, b3, out);
}